// Round 2
// baseline (268.349 us; speedup 1.0000x reference)
//
#include <hip/hip_runtime.h>

#define DMODEL 1024
#define NHEADS 16
#define HDIM   64
#define BB     4
#define TT     2048

typedef __attribute__((ext_vector_type(8))) short bf16x8;
typedef __attribute__((ext_vector_type(4))) short bf16x4;
typedef __attribute__((ext_vector_type(4))) float f32x4;

#if __has_builtin(__builtin_amdgcn_exp2f)
#define EXP2(x) __builtin_amdgcn_exp2f(x)
#else
#define EXP2(x) __expf(0.69314718f * (x))
#endif

// 0.125 * log2(e): folded into Q at projection time
#define C1SCALE 0.18033688f

__device__ inline void async16(const void* g, void* l) {
  __builtin_amdgcn_global_load_lds(
      (const __attribute__((address_space(1))) unsigned int*)g,
      (__attribute__((address_space(3))) unsigned int*)l,
      16, 0, 0);
}

__device__ inline unsigned short f2bf(float x) {
  union { float f; unsigned int u; } c; c.f = x;
  unsigned int r = (c.u + 0x7FFFu + ((c.u >> 16) & 1u)) >> 16;
  return (unsigned short)r;
}

// pack two fp32 -> bf16x2, TRUNCATING (P >= 0; identical truncation feeds both
// numerator (PV) and denominator (P*ones) so the uniform bias cancels in O)
__device__ inline unsigned int pkbf(float x, float y) {
  union { float f; unsigned int u; } a, b; a.f = x; b.f = y;
  return __builtin_amdgcn_perm(b.u, a.u, 0x07060302u);
}

// One fused conversion kernel: x (8192 blk), wq/wk/wv -> wqkvb, wo -> wob (1024 blk each)
__global__ __launch_bounds__(256) void cvt_all(
    const float* __restrict__ x,  const float* __restrict__ wq,
    const float* __restrict__ wk, const float* __restrict__ wv,
    const float* __restrict__ wo,
    unsigned short* __restrict__ xb, unsigned short* __restrict__ wqkvb,
    unsigned short* __restrict__ wob)
{
  int bid = blockIdx.x;
  const float* src; unsigned short* dst; size_t off;
  if (bid < 8192) { src = x; dst = xb; off = (size_t)bid * 1024; }
  else {
    int w = (bid - 8192) >> 10, r = (bid - 8192) & 1023;
    off = (size_t)r * 1024;
    if (w == 0)      { src = wq; dst = wqkvb; }
    else if (w == 1) { src = wk; dst = wqkvb + 1048576; }
    else if (w == 2) { src = wv; dst = wqkvb + 2097152; }
    else             { src = wo; dst = wob; }
  }
  size_t i = off + threadIdx.x * 4;
  float4 v = *(const float4*)(src + i);
  ushort4 o;
  o.x = f2bf(v.x); o.y = f2bf(v.y); o.z = f2bf(v.z); o.w = f2bf(v.w);
  *(ushort4*)(dst + i) = o;
}

// Fused QKV projection, 8-phase-style schedule (T3+T4+T5):
// BM=256 x BN=128, BK=64, 8 waves as 2M(128 rows) x 4N(32 cols), per-wave
// tile 128x32 (acc = 8x2 f32x4). Triple-buffered LDS (144 KiB), 4 phases
// per K-tile: {ds_read 2 m-frags || issue 2 async16 of tile t+2 -> barrier ->
// lgkmcnt(0) -> setprio(1) 8xMFMA setprio(0) -> barrier}. Counted
// s_waitcnt vmcnt(6) at tile entry (tile t+1's 6 loads stay in flight);
// vmcnt(0) only on the last tile. XOR-8 both-sides swizzle as before
// (conflict-free, verified 0 bank conflicts). Grid (32, 24): same-m blocks
// spaced 32 apart (== 0 mod 8) -> same XCD -> A-tile L2 reuse.
// Q output pre-scaled by C1SCALE.
__global__ __launch_bounds__(512, 2) void gemm_qkv(
    const unsigned short* __restrict__ A, const unsigned short* __restrict__ W,
    unsigned short* __restrict__ qw, unsigned short* __restrict__ kw,
    unsigned short* __restrict__ vtw)
{
  __shared__ unsigned short As[3][256 * 64];   // 96 KB
  __shared__ unsigned short Bs[3][128 * 64];   // 48 KB
  const int tid  = threadIdx.x;
  const int lane = tid & 63;
  const int wave = tid >> 6;           // 0..7
  const int lo   = lane & 15, q4 = lane >> 4;
  const int lo7  = lane & 7;
  const int wm   = wave >> 2;          // 0..1: 128-row half
  const int wn   = wave & 3;           // 0..3: 32-col quarter
  const int m0 = blockIdx.x * 256;
  const int nb = blockIdx.y;           // 0..23
  const int n0 = nb * 128;
  const int mid = nb >> 3;

  f32x4 acc[8][2] = {};

  auto stageA = [&](int k0, int buf, int i) {
    int ci = i * 512 + tid;            // 0..2047
    int row = ci >> 3;
    int c = (ci & 7) ^ (row & 7);
    async16(A + (size_t)(m0 + row) * DMODEL + k0 + c * 8, (char*)As[buf] + ci * 16);
  };
  auto stageB = [&](int k0, int buf, int i) {
    int ci = i * 512 + tid;            // 0..1023
    int row = ci >> 3;
    int c = (ci & 7) ^ (row & 7);
    async16(W + (size_t)(n0 + row) * DMODEL + k0 + c * 8, (char*)Bs[buf] + ci * 16);
  };
  auto stage_all = [&](int k0, int buf) {
    stageA(k0, buf, 0); stageA(k0, buf, 1); stageA(k0, buf, 2); stageA(k0, buf, 3);
    stageB(k0, buf, 0); stageB(k0, buf, 1);
  };

  stage_all(0, 0);
  stage_all(64, 1);

  const int NT = DMODEL / 64;          // 16
  int cur = 0;
  for (int t = 0; t < NT; ++t) {
    if (t + 1 < NT) asm volatile("s_waitcnt vmcnt(6)" ::: "memory");
    else            asm volatile("s_waitcnt vmcnt(0)" ::: "memory");
    __builtin_amdgcn_s_barrier();      // all waves' tile-t loads resident

    const unsigned short* Ab = As[cur];
    const unsigned short* Bb = Bs[cur];
    const int nxt = (cur + 2 >= 3) ? cur - 1 : cur + 2;
    const int k2 = (t + 2) * 64;
    const bool pre = (t + 2 < NT);

    bf16x8 bfr[2][2];
#pragma unroll
    for (int p = 0; p < 4; ++p) {
      bf16x8 af[2][2];
#pragma unroll
      for (int j = 0; j < 2; ++j)
#pragma unroll
        for (int kk = 0; kk < 2; ++kk)
          af[j][kk] = *(const bf16x8*)&Ab[(wm * 128 + (p * 2 + j) * 16 + lo) * 64 + ((kk * 4 + q4) ^ lo7) * 8];
      if (p == 0) {
#pragma unroll
        for (int nf = 0; nf < 2; ++nf)
#pragma unroll
          for (int kk = 0; kk < 2; ++kk)
            bfr[nf][kk] = *(const bf16x8*)&Bb[(wn * 32 + nf * 16 + lo) * 64 + ((kk * 4 + q4) ^ lo7) * 8];
      }
      if (pre) {
        if      (p == 0) { stageA(k2, nxt, 0); stageA(k2, nxt, 1); }
        else if (p == 1) { stageA(k2, nxt, 2); stageA(k2, nxt, 3); }
        else if (p == 2) { stageB(k2, nxt, 0); stageB(k2, nxt, 1); }
      }
      __builtin_amdgcn_s_barrier();
      asm volatile("s_waitcnt lgkmcnt(0)" ::: "memory");
      __builtin_amdgcn_sched_barrier(0);
      __builtin_amdgcn_s_setprio(1);
#pragma unroll
      for (int j = 0; j < 2; ++j)
#pragma unroll
        for (int nf = 0; nf < 2; ++nf)
#pragma unroll
          for (int kk = 0; kk < 2; ++kk)
            acc[p * 2 + j][nf] = __builtin_amdgcn_mfma_f32_16x16x32_bf16(af[j][kk], bfr[nf][kk], acc[p * 2 + j][nf], 0, 0, 0);
      __builtin_amdgcn_s_setprio(0);
      __builtin_amdgcn_s_barrier();
    }
    cur = (cur + 1 == 3) ? 0 : cur + 1;
  }

  unsigned short* dst = (mid == 0) ? qw : (mid == 1) ? kw : vtw;
  const float sc = (mid == 0) ? C1SCALE : 1.0f;
#pragma unroll
  for (int mf = 0; mf < 8; ++mf) {
#pragma unroll
    for (int nf = 0; nf < 2; ++nf) {
#pragma unroll
      for (int r = 0; r < 4; ++r) {
        int m = m0 + wm * 128 + mf * 16 + q4 * 4 + r;
        int nl = ((nb & 7) * 128) + wn * 32 + nf * 16 + lo;
        float v = acc[mf][nf][r] * sc;
        int b = m >> 11, t = m & (TT - 1);
        int h = nl >> 6, d = nl & 63;
        if (mid == 2)
          dst[(((size_t)(b * NHEADS + h)) * HDIM + d) * TT + t] = f2bf(v);
        else
          dst[(((size_t)(b * NHEADS + h)) * TT + t) * HDIM + d] = f2bf(v);
      }
    }
  }
}

// Output projection: C = A W^T + bias, fp32 out. Same 8-phase-style schedule.
// Grid (32, 8) = 256 blocks = exactly one round of 256 CUs.
__global__ __launch_bounds__(512, 2) void gemm_out(
    const unsigned short* __restrict__ A, const unsigned short* __restrict__ W,
    const float* __restrict__ bias, float* __restrict__ C)
{
  __shared__ unsigned short As[3][256 * 64];
  __shared__ unsigned short Bs[3][128 * 64];
  const int tid  = threadIdx.x;
  const int lane = tid & 63;
  const int wave = tid >> 6;
  const int lo   = lane & 15, q4 = lane >> 4;
  const int lo7  = lane & 7;
  const int wm   = wave >> 2;
  const int wn   = wave & 3;
  const int m0 = blockIdx.x * 256, n0 = blockIdx.y * 128;

  f32x4 acc[8][2] = {};

  auto stageA = [&](int k0, int buf, int i) {
    int ci = i * 512 + tid;
    int row = ci >> 3;
    int c = (ci & 7) ^ (row & 7);
    async16(A + (size_t)(m0 + row) * DMODEL + k0 + c * 8, (char*)As[buf] + ci * 16);
  };
  auto stageB = [&](int k0, int buf, int i) {
    int ci = i * 512 + tid;
    int row = ci >> 3;
    int c = (ci & 7) ^ (row & 7);
    async16(W + (size_t)(n0 + row) * DMODEL + k0 + c * 8, (char*)Bs[buf] + ci * 16);
  };
  auto stage_all = [&](int k0, int buf) {
    stageA(k0, buf, 0); stageA(k0, buf, 1); stageA(k0, buf, 2); stageA(k0, buf, 3);
    stageB(k0, buf, 0); stageB(k0, buf, 1);
  };

  stage_all(0, 0);
  stage_all(64, 1);

  const int NT = DMODEL / 64;
  int cur = 0;
  for (int t = 0; t < NT; ++t) {
    if (t + 1 < NT) asm volatile("s_waitcnt vmcnt(6)" ::: "memory");
    else            asm volatile("s_waitcnt vmcnt(0)" ::: "memory");
    __builtin_amdgcn_s_barrier();

    const unsigned short* Ab = As[cur];
    const unsigned short* Bb = Bs[cur];
    const int nxt = (cur + 2 >= 3) ? cur - 1 : cur + 2;
    const int k2 = (t + 2) * 64;
    const bool pre = (t + 2 < NT);

    bf16x8 bfr[2][2];
#pragma unroll
    for (int p = 0; p < 4; ++p) {
      bf16x8 af[2][2];
#pragma unroll
      for (int j = 0; j < 2; ++j)
#pragma unroll
        for (int kk = 0; kk < 2; ++kk)
          af[j][kk] = *(const bf16x8*)&Ab[(wm * 128 + (p * 2 + j) * 16 + lo) * 64 + ((kk * 4 + q4) ^ lo7) * 8];
      if (p == 0) {
#pragma unroll
        for (int nf = 0; nf < 2; ++nf)
#pragma unroll
          for (int kk = 0; kk < 2; ++kk)
            bfr[nf][kk] = *(const bf16x8*)&Bb[(wn * 32 + nf * 16 + lo) * 64 + ((kk * 4 + q4) ^ lo7) * 8];
      }
      if (pre) {
        if      (p == 0) { stageA(k2, nxt, 0); stageA(k2, nxt, 1); }
        else if (p == 1) { stageA(k2, nxt, 2); stageA(k2, nxt, 3); }
        else if (p == 2) { stageB(k2, nxt, 0); stageB(k2, nxt, 1); }
      }
      __builtin_amdgcn_s_barrier();
      asm volatile("s_waitcnt lgkmcnt(0)" ::: "memory");
      __builtin_amdgcn_sched_barrier(0);
      __builtin_amdgcn_s_setprio(1);
#pragma unroll
      for (int j = 0; j < 2; ++j)
#pragma unroll
        for (int nf = 0; nf < 2; ++nf)
#pragma unroll
          for (int kk = 0; kk < 2; ++kk)
            acc[p * 2 + j][nf] = __builtin_amdgcn_mfma_f32_16x16x32_bf16(af[j][kk], bfr[nf][kk], acc[p * 2 + j][nf], 0, 0, 0);
      __builtin_amdgcn_s_setprio(0);
      __builtin_amdgcn_s_barrier();
    }
    cur = (cur + 1 == 3) ? 0 : cur + 1;
  }

#pragma unroll
  for (int mf = 0; mf < 8; ++mf)
#pragma unroll
    for (int nf = 0; nf < 2; ++nf)
#pragma unroll
      for (int r = 0; r < 4; ++r) {
        int m = m0 + wm * 128 + mf * 16 + q4 * 4 + r;
        int n = n0 + wn * 32 + nf * 16 + lo;
        C[(size_t)m * DMODEL + n] = acc[mf][nf][r] + bias[n];
      }
}

// Flash attention + ALiBi, fixed-scale softmax, register-resident P (S^T trick),
// exact per-head sliding window (D = 28 exp2-bits), htab load-balancing.
// PV path at K=32: S^T output (4 consecutive keys per lane, q4*4+r) is
// redistributed to the 16x16x32 A-fragment layout (q4*8+j) with a 4x4
// lane-group transpose via permlane32_swap + permlane16_swap. Same truncated
// bf16 P feeds PV and the ones-rowsum, preserving the truncation-cancel.
__global__ __launch_bounds__(256, 4) void attn_kernel(
    const unsigned short* __restrict__ Q, const unsigned short* __restrict__ K,
    const unsigned short* __restrict__ Vt, unsigned short* __restrict__ O)
{
  __shared__ unsigned short Ks[2][64 * 64];
  __shared__ unsigned short Vs[2][64 * 64];

  const int tid = threadIdx.x, lane = tid & 63, wave = tid >> 6;
  const int lo = lane & 15, q4 = lane >> 4;
  const int lo7 = lane & 7;
  const int bid = blockIdx.x;
  // htab[s] packed as nibbles: {12,13,14,15,11,10,9,8,4,5,6,7,1,0,2,3}
  const int h  = (int)((0x3201765489ABFEDCull >> ((bid >> 6) * 4)) & 15);
  const int qb = bid & 15;
  const int b  = (bid >> 4) & 3;
  const int bh = b * NHEADS + h;
  const float slopeL = exp2f(-0.5f * (float)(h + 1)) * 1.44269504f;
  const int q0 = qb * 128;
  const int wq0 = q0 + wave * 32;

  // per-head window: keep tiles with min distance <= D = 28 exp2-bits
  const int D = (int)(19.407f * exp2f(0.5f * (float)(h + 1)));
  int tlo = q0 - D;
  const int ktlo = (tlo <= 0) ? 0 : (tlo >> 6);
  int thi = (q0 + 127 + D) >> 6;
  const int kthi = (thi > TT / 64 - 1) ? TT / 64 - 1 : thi;

  // Q fragments (B-operand of S^T): 2 m-tiles x 2 k-halves
  bf16x8 qf[2][2];
#pragma unroll
  for (int m = 0; m < 2; ++m)
#pragma unroll
    for (int hh = 0; hh < 2; ++hh)
      qf[m][hh] = *(const bf16x8*)(Q + ((size_t)bh * TT + wq0 + m * 16 + lo) * HDIM + hh * 32 + q4 * 8);

  // ones B-fragment for row-sum (K=32): column n==0 only
  bf16x8 ones8;
  {
    short o = (lo == 0) ? (short)0x3F80 : (short)0;
    ones8 = bf16x8{o, o, o, o, o, o, o, o};
  }

  f32x4 Oacc[2][4];
  f32x4 lacc[2];
#pragma unroll
  for (int m = 0; m < 2; ++m) {
    lacc[m] = f32x4{0.f, 0.f, 0.f, 0.f};
#pragma unroll
    for (int nd = 0; nd < 4; ++nd) Oacc[m][nd] = f32x4{0.f, 0.f, 0.f, 0.f};
  }

  // hoisted distance base: qrow - key = eb[m][r] - (kt*64 + ns*16)
  float eb[2][4];
#pragma unroll
  for (int m = 0; m < 2; ++m)
#pragma unroll
    for (int r = 0; r < 4; ++r)
      eb[m][r] = (float)(wq0 + m * 16 + lo - q4 * 4 - r);

  const unsigned short* kbh = K + (size_t)bh * TT * HDIM;
  const unsigned short* vbh = Vt + (size_t)bh * HDIM * TT;

  auto stage = [&](int kt, int buf) {
#pragma unroll
    for (int i = 0; i < 2; ++i) {
      int ci = i * 256 + tid;
      int row = ci >> 3;
      int c = (ci & 7) ^ (row & 7);
      async16(kbh + (size_t)(kt * 64 + row) * HDIM + c * 8, (char*)Ks[buf] + ci * 16);
      async16(vbh + (size_t)row * TT + kt * 64 + c * 8,     (char*)Vs[buf] + ci * 16);
    }
  };

  stage(ktlo, 0);

  for (int kt = ktlo; kt <= kthi; ++kt) {
    const int buf = (kt - ktlo) & 1;
    __syncthreads();  // tile kt staged; all waves done reading buf^1
    if (kt < kthi) stage(kt + 1, buf ^ 1);

#pragma unroll
    for (int pp = 0; pp < 2; ++pp) {       // 32-key half-tiles
      unsigned int ua[2][2], ub[2][2];     // [hns][m]: packed words (r0,r1)/(r2,r3)
#pragma unroll
      for (int hns = 0; hns < 2; ++hns) {
        const int ns = pp * 2 + hns;
        const int krow = (ns * 16 + lo) * 64;
        bf16x8 kf0 = *(const bf16x8*)&Ks[buf][krow + ((q4) ^ lo7) * 8];
        bf16x8 kf1 = *(const bf16x8*)&Ks[buf][krow + ((4 + q4) ^ lo7) * 8];
        const float kb = (float)(kt * 64 + ns * 16);
#pragma unroll
        for (int m = 0; m < 2; ++m) {
          // S^T: D[key][qrow], lane: col=lo=qrow, rows=q4*4+r=key-in-block
          f32x4 a = {0.f, 0.f, 0.f, 0.f};
          __builtin_amdgcn_s_setprio(1);
          a = __builtin_amdgcn_mfma_f32_16x16x32_bf16(kf0, qf[m][0], a, 0, 0, 0);
          a = __builtin_amdgcn_mfma_f32_16x16x32_bf16(kf1, qf[m][1], a, 0, 0, 0);
          __builtin_amdgcn_s_setprio(0);
          float pv[4];
#pragma unroll
          for (int r = 0; r < 4; ++r) {
            float w = eb[m][r] - kb;                      // qrow - key
            pv[r] = EXP2(fmaf(-slopeL, fabsf(w), a[r]));  // a already scaled by c1
          }
          ua[hns][m] = pkbf(pv[0], pv[1]);
          ub[hns][m] = pkbf(pv[2], pv[3]);
        }
      }

      // lane-group transpose: (q4'*4+r keys) -> (q4*8+j keys) K=32 A-fragment
      bf16x8 paf[2];
#pragma unroll
      for (int m = 0; m < 2; ++m) {
        unsigned int w0 = ua[0][m], w2 = ua[1][m];
        unsigned int w1 = ub[0][m], w3 = ub[1][m];
        asm("v_permlane32_swap_b32 %0, %1" : "+v"(w0), "+v"(w2));
        asm("v_permlane16_swap_b32 %0, %1" : "+v"(w0), "+v"(w2));  // w0=W0 w2=W2
        asm("v_permlane32_swap_b32 %0, %1" : "+v"(w1), "+v"(w3));
        asm("v_permlane16_swap_b32 %0, %1" : "+v"(w1), "+v"(w3));  // w1=W1 w3=W3
        union { bf16x8 v; unsigned int u[4]; } U;
        U.u[0] = w0; U.u[1] = w1; U.u[2] = w2; U.u[3] = w3;
        paf[m] = U.v;
      }

      // PV + row-sum at K=32; B = Vt rows (n=d, k=key in 32-key half-tile)
#pragma unroll
      for (int nd = 0; nd < 4; ++nd) {
        const int row = nd * 16 + lo;
        bf16x8 vb = *(const bf16x8*)&Vs[buf][row * 64 + ((pp * 4 + q4) ^ lo7) * 8];
        __builtin_amdgcn_s_setprio(1);
#pragma unroll
        for (int m = 0; m < 2; ++m)
          Oacc[m][nd] = __builtin_amdgcn_mfma_f32_16x16x32_bf16(paf[m], vb, Oacc[m][nd], 0, 0, 0);
        __builtin_amdgcn_s_setprio(0);
      }
#pragma unroll
      for (int m = 0; m < 2; ++m)
        lacc[m] = __builtin_amdgcn_mfma_f32_16x16x32_bf16(paf[m], ones8, lacc[m], 0, 0, 0);
    }
  }

  // epilogue: broadcast row-sums from lo==0 lanes, normalize, store
#pragma unroll
  for (int m = 0; m < 2; ++m)
#pragma unroll
    for (int r = 0; r < 4; ++r) {
      float l = __shfl(lacc[m][r], lane & 48);
      float inv = 1.f / l;
      int t = wq0 + m * 16 + q4 * 4 + r;
#pragma unroll
      for (int nd = 0; nd < 4; ++nd) {
        int d = nd * 16 + lo;
        O[((size_t)(b * TT + t)) * DMODEL + h * HDIM + d] = f2bf(Oacc[m][nd][r] * inv);
      }
    }
}

extern "C" void kernel_launch(void* const* d_in, const int* in_sizes, int n_in,
                              void* d_out, int out_size, void* d_ws, size_t ws_size,
                              hipStream_t stream) {
  const float* x  = (const float*)d_in[0];
  const float* wq = (const float*)d_in[1];
  const float* wk = (const float*)d_in[2];
  const float* wv = (const float*)d_in[3];
  const float* wo = (const float*)d_in[4];
  const float* bo = (const float*)d_in[5];
  float* out = (float*)d_out;

  char* ws = (char*)d_ws;
  const size_t seg  = (size_t)BB * TT * DMODEL * sizeof(unsigned short);  // 16.78 MB
  const size_t wseg = (size_t)DMODEL * DMODEL * sizeof(unsigned short);   // 2 MB
  unsigned short* qw    = (unsigned short*)(ws);
  unsigned short* kw    = (unsigned short*)(ws + seg);
  unsigned short* vtw   = (unsigned short*)(ws + 2 * seg);
  unsigned short* ow    = (unsigned short*)(ws + 3 * seg);
  unsigned short* xb    = (unsigned short*)(ws + 4 * seg);
  unsigned short* wqkvb = (unsigned short*)(ws + 5 * seg);
  unsigned short* wob   = (unsigned short*)(ws + 5 * seg + 3 * wseg);

  cvt_all<<<dim3(8192 + 4096), dim3(256), 0, stream>>>(x, wq, wk, wv, wo, xb, wqkvb, wob);

  gemm_qkv<<<dim3(32, 24), dim3(512), 0, stream>>>(xb, wqkvb, qw, kw, vtw);

  attn_kernel<<<dim3(BB * NHEADS * (TT / 128)), dim3(256), 0, stream>>>(qw, kw, vtw, ow);

  gemm_out<<<dim3(32, 8), dim3(512), 0, stream>>>(ow, wob, bo, out);
}

// Round 3
// 243.980 us; speedup vs baseline: 1.0999x; 1.0999x over previous
//
#include <hip/hip_runtime.h>

#define DMODEL 1024
#define NHEADS 16
#define HDIM   64
#define BB     4
#define TT     2048

typedef __attribute__((ext_vector_type(8))) short bf16x8;
typedef __attribute__((ext_vector_type(4))) short bf16x4;
typedef __attribute__((ext_vector_type(4))) float f32x4;

#if __has_builtin(__builtin_amdgcn_exp2f)
#define EXP2(x) __builtin_amdgcn_exp2f(x)
#else
#define EXP2(x) __expf(0.69314718f * (x))
#endif

// 0.125 * log2(e): folded into Q at projection time
#define C1SCALE 0.18033688f

__device__ inline void async16(const void* g, void* l) {
  __builtin_amdgcn_global_load_lds(
      (const __attribute__((address_space(1))) unsigned int*)g,
      (__attribute__((address_space(3))) unsigned int*)l,
      16, 0, 0);
}

__device__ inline unsigned short f2bf(float x) {
  union { float f; unsigned int u; } c; c.f = x;
  unsigned int r = (c.u + 0x7FFFu + ((c.u >> 16) & 1u)) >> 16;
  return (unsigned short)r;
}

// pack two fp32 -> bf16x2, TRUNCATING (P >= 0; identical truncation feeds both
// numerator (PV) and denominator (P*ones) so the uniform bias cancels in O)
__device__ inline unsigned int pkbf(float x, float y) {
  union { float f; unsigned int u; } a, b; a.f = x; b.f = y;
  return __builtin_amdgcn_perm(b.u, a.u, 0x07060302u);
}

// One fused conversion kernel: x (8192 blk), wq/wk/wv -> wqkvb, wo -> wob (1024 blk each)
__global__ __launch_bounds__(256) void cvt_all(
    const float* __restrict__ x,  const float* __restrict__ wq,
    const float* __restrict__ wk, const float* __restrict__ wv,
    const float* __restrict__ wo,
    unsigned short* __restrict__ xb, unsigned short* __restrict__ wqkvb,
    unsigned short* __restrict__ wob)
{
  int bid = blockIdx.x;
  const float* src; unsigned short* dst; size_t off;
  if (bid < 8192) { src = x; dst = xb; off = (size_t)bid * 1024; }
  else {
    int w = (bid - 8192) >> 10, r = (bid - 8192) & 1023;
    off = (size_t)r * 1024;
    if (w == 0)      { src = wq; dst = wqkvb; }
    else if (w == 1) { src = wk; dst = wqkvb + 1048576; }
    else if (w == 2) { src = wv; dst = wqkvb + 2097152; }
    else             { src = wo; dst = wob; }
  }
  size_t i = off + threadIdx.x * 4;
  float4 v = *(const float4*)(src + i);
  ushort4 o;
  o.x = f2bf(v.x); o.y = f2bf(v.y); o.z = f2bf(v.z); o.w = f2bf(v.w);
  *(ushort4*)(dst + i) = o;
}

// Fused QKV projection: A = xb (8192x1024), W = wqkvb (3072x1024), y = A W^T.
// R8 structure: 8 waves x (32x64 per-wave tile, 32 AGPR acc), BK=64,
// XOR-8 swizzle (conflict-free), double-buffered async staging.
// Grid (64, 24): blockIdx.x = m-tile so same-m blocks (which share the A tile)
// have bids spaced 64 apart -> same XCD under round-robin -> A served from L2.
// Q output pre-scaled by C1SCALE.
__global__ __launch_bounds__(512, 4) void gemm_qkv(
    const unsigned short* __restrict__ A, const unsigned short* __restrict__ W,
    unsigned short* __restrict__ qw, unsigned short* __restrict__ kw,
    unsigned short* __restrict__ vtw)
{
  __shared__ unsigned short As[2][128 * 64];
  __shared__ unsigned short Bs[2][128 * 64];
  const int tid  = threadIdx.x;
  const int lane = tid & 63;
  const int wave = tid >> 6;           // 0..7
  const int lo   = lane & 15, q4 = lane >> 4;
  const int lo7  = lane & 7;
  const int wm   = wave & 3, wn = wave >> 2;  // 32-row quarter, 64-col half
  const int m0 = blockIdx.x * 128;            // m-tile on x (XCD locality)
  const int nb = blockIdx.y;                  // 0..23
  const int n0 = nb * 128;
  const int mid = nb >> 3;

  f32x4 acc[2][4] = {};

  auto stage = [&](int k0, int buf) {
#pragma unroll
    for (int i = 0; i < 2; ++i) {
      int ci = i * 512 + tid;          // 0..1023
      int row = ci >> 3;
      int c = (ci & 7) ^ (row & 7);
      async16(A + (size_t)(m0 + row) * DMODEL + k0 + c * 8, (char*)As[buf] + ci * 16);
      async16(W + (size_t)(n0 + row) * DMODEL + k0 + c * 8, (char*)Bs[buf] + ci * 16);
    }
  };

  stage(0, 0);
  for (int it = 0; it < DMODEL / 64; ++it) {
    const int buf = it & 1;
    __syncthreads();  // stage(it), issued one compute phase ago, now resident
    if (it + 1 < DMODEL / 64) stage((it + 1) * 64, buf ^ 1);
#pragma unroll
    for (int hh = 0; hh < 2; ++hh) {
      bf16x8 af[2], bf[4];
#pragma unroll
      for (int mi = 0; mi < 2; ++mi)
        af[mi] = *(const bf16x8*)&As[buf][(wm * 32 + mi * 16 + lo) * 64 + ((hh * 4 + q4) ^ lo7) * 8];
#pragma unroll
      for (int ni = 0; ni < 4; ++ni)
        bf[ni] = *(const bf16x8*)&Bs[buf][(wn * 64 + ni * 16 + lo) * 64 + ((hh * 4 + q4) ^ lo7) * 8];
#pragma unroll
      for (int mi = 0; mi < 2; ++mi)
#pragma unroll
        for (int ni = 0; ni < 4; ++ni)
          acc[mi][ni] = __builtin_amdgcn_mfma_f32_16x16x32_bf16(af[mi], bf[ni], acc[mi][ni], 0, 0, 0);
    }
  }

  unsigned short* dst = (mid == 0) ? qw : (mid == 1) ? kw : vtw;
  const float sc = (mid == 0) ? C1SCALE : 1.0f;
#pragma unroll
  for (int mi = 0; mi < 2; ++mi) {
#pragma unroll
    for (int ni = 0; ni < 4; ++ni) {
#pragma unroll
      for (int r = 0; r < 4; ++r) {
        int m = m0 + wm * 32 + mi * 16 + q4 * 4 + r;
        int nl = ((nb & 7) * 128) + wn * 64 + ni * 16 + lo;
        float v = acc[mi][ni][r] * sc;
        int b = m >> 11, t = m & (TT - 1);
        int h = nl >> 6, d = nl & 63;
        if (mid == 2)
          dst[(((size_t)(b * NHEADS + h)) * HDIM + d) * TT + t] = f2bf(v);
        else
          dst[(((size_t)(b * NHEADS + h)) * TT + t) * HDIM + d] = f2bf(v);
      }
    }
  }
}

// Output projection: C = A W^T + bias, fp32 out. Same R8 dbuf structure,
// grid (64, 8) with m on x for XCD locality of the A (ow) tile.
__global__ __launch_bounds__(512, 4) void gemm_out(
    const unsigned short* __restrict__ A, const unsigned short* __restrict__ W,
    const float* __restrict__ bias, float* __restrict__ C)
{
  __shared__ unsigned short As[2][128 * 64];
  __shared__ unsigned short Bs[2][128 * 64];
  const int tid  = threadIdx.x;
  const int lane = tid & 63;
  const int wave = tid >> 6;
  const int lo   = lane & 15, q4 = lane >> 4;
  const int lo7  = lane & 7;
  const int wm   = wave & 3, wn = wave >> 2;
  const int m0 = blockIdx.x * 128, n0 = blockIdx.y * 128;

  f32x4 acc[2][4] = {};

  auto stage = [&](int k0, int buf) {
#pragma unroll
    for (int i = 0; i < 2; ++i) {
      int ci = i * 512 + tid;
      int row = ci >> 3;
      int c = (ci & 7) ^ (row & 7);
      async16(A + (size_t)(m0 + row) * DMODEL + k0 + c * 8, (char*)As[buf] + ci * 16);
      async16(W + (size_t)(n0 + row) * DMODEL + k0 + c * 8, (char*)Bs[buf] + ci * 16);
    }
  };

  stage(0, 0);
  for (int it = 0; it < DMODEL / 64; ++it) {
    const int buf = it & 1;
    __syncthreads();
    if (it + 1 < DMODEL / 64) stage((it + 1) * 64, buf ^ 1);
#pragma unroll
    for (int hh = 0; hh < 2; ++hh) {
      bf16x8 af[2], bf[4];
#pragma unroll
      for (int mi = 0; mi < 2; ++mi)
        af[mi] = *(const bf16x8*)&As[buf][(wm * 32 + mi * 16 + lo) * 64 + ((hh * 4 + q4) ^ lo7) * 8];
#pragma unroll
      for (int ni = 0; ni < 4; ++ni)
        bf[ni] = *(const bf16x8*)&Bs[buf][(wn * 64 + ni * 16 + lo) * 64 + ((hh * 4 + q4) ^ lo7) * 8];
#pragma unroll
      for (int mi = 0; mi < 2; ++mi)
#pragma unroll
        for (int ni = 0; ni < 4; ++ni)
          acc[mi][ni] = __builtin_amdgcn_mfma_f32_16x16x32_bf16(af[mi], bf[ni], acc[mi][ni], 0, 0, 0);
    }
  }

#pragma unroll
  for (int mi = 0; mi < 2; ++mi)
#pragma unroll
    for (int ni = 0; ni < 4; ++ni)
#pragma unroll
      for (int r = 0; r < 4; ++r) {
        int m = m0 + wm * 32 + mi * 16 + q4 * 4 + r;
        int n = n0 + wn * 64 + ni * 16 + lo;
        C[(size_t)m * DMODEL + n] = acc[mi][ni][r] + bias[n];
      }
}

// Flash attention + ALiBi, fixed-scale softmax, register-resident P (S^T trick),
// exact per-head sliding window, htab load-balancing.
// 8 waves x 32 q-rows = 256-row Q-block (halves K/V window re-reads vs 128):
// per-wave math, fragments, swizzles, epilogue identical to the verified
// 4-wave version; only the block decomposition and staging indexing change.
// PV at K=32 via permlane 4x4 lane-group transpose of the S^T output.
__global__ __launch_bounds__(512, 4) void attn_kernel(
    const unsigned short* __restrict__ Q, const unsigned short* __restrict__ K,
    const unsigned short* __restrict__ Vt, unsigned short* __restrict__ O)
{
  __shared__ unsigned short Ks[2][64 * 64];
  __shared__ unsigned short Vs[2][64 * 64];

  const int tid = threadIdx.x, lane = tid & 63, wave = tid >> 6;  // wave 0..7
  const int lo = lane & 15, q4 = lane >> 4;
  const int lo7 = lane & 7;
  const int bid = blockIdx.x;  // 512 blocks: 16 head-slots x 4 b x 8 qb
  // htab[s] packed as nibbles: {12,13,14,15,11,10,9,8,4,5,6,7,1,0,2,3}
  const int h  = (int)((0x3201765489ABFEDCull >> ((bid >> 5) * 4)) & 15);
  const int qb = bid & 7;
  const int b  = (bid >> 3) & 3;
  const int bh = b * NHEADS + h;
  const float slopeL = exp2f(-0.5f * (float)(h + 1)) * 1.44269504f;
  const int q0 = qb * 256;
  const int wq0 = q0 + wave * 32;

  // per-head window: keep tiles with min distance <= D = 28 exp2-bits
  const int D = (int)(19.407f * exp2f(0.5f * (float)(h + 1)));
  int tlo = q0 - D;
  const int ktlo = (tlo <= 0) ? 0 : (tlo >> 6);
  int thi = (q0 + 255 + D) >> 6;
  const int kthi = (thi > TT / 64 - 1) ? TT / 64 - 1 : thi;

  // Q fragments (B-operand of S^T): 2 m-tiles x 2 k-halves
  bf16x8 qf[2][2];
#pragma unroll
  for (int m = 0; m < 2; ++m)
#pragma unroll
    for (int hh = 0; hh < 2; ++hh)
      qf[m][hh] = *(const bf16x8*)(Q + ((size_t)bh * TT + wq0 + m * 16 + lo) * HDIM + hh * 32 + q4 * 8);

  // ones B-fragment for row-sum (K=32): column n==0 only
  bf16x8 ones8;
  {
    short o = (lo == 0) ? (short)0x3F80 : (short)0;
    ones8 = bf16x8{o, o, o, o, o, o, o, o};
  }

  f32x4 Oacc[2][4];
  f32x4 lacc[2];
#pragma unroll
  for (int m = 0; m < 2; ++m) {
    lacc[m] = f32x4{0.f, 0.f, 0.f, 0.f};
#pragma unroll
    for (int nd = 0; nd < 4; ++nd) Oacc[m][nd] = f32x4{0.f, 0.f, 0.f, 0.f};
  }

  // hoisted distance base: qrow - key = eb[m][r] - (kt*64 + ns*16)
  float eb[2][4];
#pragma unroll
  for (int m = 0; m < 2; ++m)
#pragma unroll
    for (int r = 0; r < 4; ++r)
      eb[m][r] = (float)(wq0 + m * 16 + lo - q4 * 4 - r);

  const unsigned short* kbh = K + (size_t)bh * TT * HDIM;
  const unsigned short* vbh = Vt + (size_t)bh * HDIM * TT;

  // 512 threads: exactly one 16B chunk per thread per array per tile
  auto stage = [&](int kt, int buf) {
    int ci = tid;                      // 0..511
    int row = ci >> 3;
    int c = (ci & 7) ^ (row & 7);
    async16(kbh + (size_t)(kt * 64 + row) * HDIM + c * 8, (char*)Ks[buf] + ci * 16);
    async16(vbh + (size_t)row * TT + kt * 64 + c * 8,     (char*)Vs[buf] + ci * 16);
  };

  stage(ktlo, 0);

  for (int kt = ktlo; kt <= kthi; ++kt) {
    const int buf = (kt - ktlo) & 1;
    __syncthreads();  // tile kt staged; all waves done reading buf^1
    if (kt < kthi) stage(kt + 1, buf ^ 1);

#pragma unroll
    for (int pp = 0; pp < 2; ++pp) {       // 32-key half-tiles
      unsigned int ua[2][2], ub[2][2];     // [hns][m]: packed words (r0,r1)/(r2,r3)
#pragma unroll
      for (int hns = 0; hns < 2; ++hns) {
        const int ns = pp * 2 + hns;
        const int krow = (ns * 16 + lo) * 64;
        bf16x8 kf0 = *(const bf16x8*)&Ks[buf][krow + ((q4) ^ lo7) * 8];
        bf16x8 kf1 = *(const bf16x8*)&Ks[buf][krow + ((4 + q4) ^ lo7) * 8];
        const float kb = (float)(kt * 64 + ns * 16);
#pragma unroll
        for (int m = 0; m < 2; ++m) {
          // S^T: D[key][qrow], lane: col=lo=qrow, rows=q4*4+r=key-in-block
          f32x4 a = {0.f, 0.f, 0.f, 0.f};
          __builtin_amdgcn_s_setprio(1);
          a = __builtin_amdgcn_mfma_f32_16x16x32_bf16(kf0, qf[m][0], a, 0, 0, 0);
          a = __builtin_amdgcn_mfma_f32_16x16x32_bf16(kf1, qf[m][1], a, 0, 0, 0);
          __builtin_amdgcn_s_setprio(0);
          float pv[4];
#pragma unroll
          for (int r = 0; r < 4; ++r) {
            float w = eb[m][r] - kb;                      // qrow - key
            pv[r] = EXP2(fmaf(-slopeL, fabsf(w), a[r]));  // a already scaled by c1
          }
          ua[hns][m] = pkbf(pv[0], pv[1]);
          ub[hns][m] = pkbf(pv[2], pv[3]);
        }
      }

      // lane-group transpose: (q4'*4+r keys) -> (q4*8+j keys) K=32 A-fragment
      bf16x8 paf[2];
#pragma unroll
      for (int m = 0; m < 2; ++m) {
        unsigned int w0 = ua[0][m], w2 = ua[1][m];
        unsigned int w1 = ub[0][m], w3 = ub[1][m];
        asm("v_permlane32_swap_b32 %0, %1" : "+v"(w0), "+v"(w2));
        asm("v_permlane16_swap_b32 %0, %1" : "+v"(w0), "+v"(w2));  // w0=W0 w2=W2
        asm("v_permlane32_swap_b32 %0, %1" : "+v"(w1), "+v"(w3));
        asm("v_permlane16_swap_b32 %0, %1" : "+v"(w1), "+v"(w3));  // w1=W1 w3=W3
        union { bf16x8 v; unsigned int u[4]; } U;
        U.u[0] = w0; U.u[1] = w1; U.u[2] = w2; U.u[3] = w3;
        paf[m] = U.v;
      }

      // PV + row-sum at K=32; B = Vt rows (n=d, k=key in 32-key half-tile)
#pragma unroll
      for (int nd = 0; nd < 4; ++nd) {
        const int row = nd * 16 + lo;
        bf16x8 vb = *(const bf16x8*)&Vs[buf][row * 64 + ((pp * 4 + q4) ^ lo7) * 8];
        __builtin_amdgcn_s_setprio(1);
#pragma unroll
        for (int m = 0; m < 2; ++m)
          Oacc[m][nd] = __builtin_amdgcn_mfma_f32_16x16x32_bf16(paf[m], vb, Oacc[m][nd], 0, 0, 0);
        __builtin_amdgcn_s_setprio(0);
      }
#pragma unroll
      for (int m = 0; m < 2; ++m)
        lacc[m] = __builtin_amdgcn_mfma_f32_16x16x32_bf16(paf[m], ones8, lacc[m], 0, 0, 0);
    }
  }

  // epilogue: broadcast row-sums from lo==0 lanes, normalize, store
#pragma unroll
  for (int m = 0; m < 2; ++m)
#pragma unroll
    for (int r = 0; r < 4; ++r) {
      float l = __shfl(lacc[m][r], lane & 48);
      float inv = 1.f / l;
      int t = wq0 + m * 16 + q4 * 4 + r;
#pragma unroll
      for (int nd = 0; nd < 4; ++nd) {
        int d = nd * 16 + lo;
        O[((size_t)(b * TT + t)) * DMODEL + h * HDIM + d] = f2bf(Oacc[m][nd][r] * inv);
      }
    }
}

extern "C" void kernel_launch(void* const* d_in, const int* in_sizes, int n_in,
                              void* d_out, int out_size, void* d_ws, size_t ws_size,
                              hipStream_t stream) {
  const float* x  = (const float*)d_in[0];
  const float* wq = (const float*)d_in[1];
  const float* wk = (const float*)d_in[2];
  const float* wv = (const float*)d_in[3];
  const float* wo = (const float*)d_in[4];
  const float* bo = (const float*)d_in[5];
  float* out = (float*)d_out;

  char* ws = (char*)d_ws;
  const size_t seg  = (size_t)BB * TT * DMODEL * sizeof(unsigned short);  // 16.78 MB
  const size_t wseg = (size_t)DMODEL * DMODEL * sizeof(unsigned short);   // 2 MB
  unsigned short* qw    = (unsigned short*)(ws);
  unsigned short* kw    = (unsigned short*)(ws + seg);
  unsigned short* vtw   = (unsigned short*)(ws + 2 * seg);
  unsigned short* ow    = (unsigned short*)(ws + 3 * seg);
  unsigned short* xb    = (unsigned short*)(ws + 4 * seg);
  unsigned short* wqkvb = (unsigned short*)(ws + 5 * seg);
  unsigned short* wob   = (unsigned short*)(ws + 5 * seg + 3 * wseg);

  cvt_all<<<dim3(8192 + 4096), dim3(256), 0, stream>>>(x, wq, wk, wv, wo, xb, wqkvb, wob);

  gemm_qkv<<<dim3(64, 24), dim3(512), 0, stream>>>(xb, wqkvb, qw, kw, vtw);

  attn_kernel<<<dim3(BB * NHEADS * (TT / 256)), dim3(512), 0, stream>>>(qw, kw, vtw, ow);

  gemm_out<<<dim3(64, 8), dim3(512), 0, stream>>>(ow, wob, bo, out);
}

// Round 5
// 233.881 us; speedup vs baseline: 1.1474x; 1.0432x over previous
//
#include <hip/hip_runtime.h>

#define DMODEL 1024
#define NHEADS 16
#define HDIM   64
#define BB     4
#define TT     2048

typedef __attribute__((ext_vector_type(8))) short bf16x8;
typedef __attribute__((ext_vector_type(4))) short bf16x4;
typedef __attribute__((ext_vector_type(4))) float f32x4;

#if __has_builtin(__builtin_amdgcn_exp2f)
#define EXP2(x) __builtin_amdgcn_exp2f(x)
#else
#define EXP2(x) __expf(0.69314718f * (x))
#endif

// 0.125 * log2(e): folded into Q at projection time
#define C1SCALE 0.18033688f

__device__ inline void async16(const void* g, void* l) {
  __builtin_amdgcn_global_load_lds(
      (const __attribute__((address_space(1))) unsigned int*)g,
      (__attribute__((address_space(3))) unsigned int*)l,
      16, 0, 0);
}

__device__ inline unsigned short f2bf(float x) {
  union { float f; unsigned int u; } c; c.f = x;
  unsigned int r = (c.u + 0x7FFFu + ((c.u >> 16) & 1u)) >> 16;
  return (unsigned short)r;
}

// pack two fp32 -> bf16x2 with RNE rounding (hardware v_cvt_pk_bf16_f32).
// lo16 = bf16(x), hi16 = bf16(y) — same layout as the old perm-based pack.
__device__ inline unsigned int pkbf_rne(float x, float y) {
  unsigned int r;
  asm("v_cvt_pk_bf16_f32 %0, %1, %2" : "=v"(r) : "v"(x), "v"(y));
  return r;
}

// One fused conversion kernel: x (8192 blk), wq/wk/wv -> wqkvb, wo -> wob (1024 blk each)
__global__ __launch_bounds__(256) void cvt_all(
    const float* __restrict__ x,  const float* __restrict__ wq,
    const float* __restrict__ wk, const float* __restrict__ wv,
    const float* __restrict__ wo,
    unsigned short* __restrict__ xb, unsigned short* __restrict__ wqkvb,
    unsigned short* __restrict__ wob)
{
  int bid = blockIdx.x;
  const float* src; unsigned short* dst; size_t off;
  if (bid < 8192) { src = x; dst = xb; off = (size_t)bid * 1024; }
  else {
    int w = (bid - 8192) >> 10, r = (bid - 8192) & 1023;
    off = (size_t)r * 1024;
    if (w == 0)      { src = wq; dst = wqkvb; }
    else if (w == 1) { src = wk; dst = wqkvb + 1048576; }
    else if (w == 2) { src = wv; dst = wqkvb + 2097152; }
    else             { src = wo; dst = wob; }
  }
  size_t i = off + threadIdx.x * 4;
  float4 v = *(const float4*)(src + i);
  ushort4 o;
  o.x = f2bf(v.x); o.y = f2bf(v.y); o.z = f2bf(v.z); o.w = f2bf(v.w);
  *(ushort4*)(dst + i) = o;
}

// Fused QKV projection: A = xb (8192x1024), W = wqkvb (3072x1024), y = A W^T.
// R8 structure: 8 waves x (32x64 per-wave tile, 32 AGPR acc), BK=64,
// XOR-8 swizzle (conflict-free), double-buffered async staging.
// Grid (64, 24): blockIdx.x = m-tile so same-m blocks (which share the A tile)
// have bids spaced 64 apart -> same XCD under round-robin -> A served from L2.
// Q output pre-scaled by C1SCALE. V-epilogue uses packed ushort4 stores
// (4 consecutive t at fixed d).
__global__ __launch_bounds__(512, 4) void gemm_qkv(
    const unsigned short* __restrict__ A, const unsigned short* __restrict__ W,
    unsigned short* __restrict__ qw, unsigned short* __restrict__ kw,
    unsigned short* __restrict__ vtw)
{
  __shared__ unsigned short As[2][128 * 64];
  __shared__ unsigned short Bs[2][128 * 64];
  const int tid  = threadIdx.x;
  const int lane = tid & 63;
  const int wave = tid >> 6;           // 0..7
  const int lo   = lane & 15, q4 = lane >> 4;
  const int lo7  = lane & 7;
  const int wm   = wave & 3, wn = wave >> 2;  // 32-row quarter, 64-col half
  const int m0 = blockIdx.x * 128;            // m-tile on x (XCD locality)
  const int nb = blockIdx.y;                  // 0..23
  const int n0 = nb * 128;
  const int mid = nb >> 3;

  f32x4 acc[2][4] = {};

  auto stage = [&](int k0, int buf) {
#pragma unroll
    for (int i = 0; i < 2; ++i) {
      int ci = i * 512 + tid;          // 0..1023
      int row = ci >> 3;
      int c = (ci & 7) ^ (row & 7);
      async16(A + (size_t)(m0 + row) * DMODEL + k0 + c * 8, (char*)As[buf] + ci * 16);
      async16(W + (size_t)(n0 + row) * DMODEL + k0 + c * 8, (char*)Bs[buf] + ci * 16);
    }
  };

  stage(0, 0);
  for (int it = 0; it < DMODEL / 64; ++it) {
    const int buf = it & 1;
    __syncthreads();  // stage(it), issued one compute phase ago, now resident
    if (it + 1 < DMODEL / 64) stage((it + 1) * 64, buf ^ 1);
#pragma unroll
    for (int hh = 0; hh < 2; ++hh) {
      bf16x8 af[2], bf[4];
#pragma unroll
      for (int mi = 0; mi < 2; ++mi)
        af[mi] = *(const bf16x8*)&As[buf][(wm * 32 + mi * 16 + lo) * 64 + ((hh * 4 + q4) ^ lo7) * 8];
#pragma unroll
      for (int ni = 0; ni < 4; ++ni)
        bf[ni] = *(const bf16x8*)&Bs[buf][(wn * 64 + ni * 16 + lo) * 64 + ((hh * 4 + q4) ^ lo7) * 8];
#pragma unroll
      for (int mi = 0; mi < 2; ++mi)
#pragma unroll
        for (int ni = 0; ni < 4; ++ni)
          acc[mi][ni] = __builtin_amdgcn_mfma_f32_16x16x32_bf16(af[mi], bf[ni], acc[mi][ni], 0, 0, 0);
    }
  }

  unsigned short* dst = (mid == 0) ? qw : (mid == 1) ? kw : vtw;
  const float sc = (mid == 0) ? C1SCALE : 1.0f;
#pragma unroll
  for (int mi = 0; mi < 2; ++mi) {
#pragma unroll
    for (int ni = 0; ni < 4; ++ni) {
      int m_ = m0 + wm * 32 + mi * 16 + q4 * 4;      // t0 (multiple of 4)
      int nl = ((nb & 7) * 128) + wn * 64 + ni * 16 + lo;
      int b_ = m_ >> 11, t_ = m_ & (TT - 1);
      int h_ = nl >> 6, d_ = nl & 63;
      if (mid == 2) {
        ushort4 o4;
        o4.x = f2bf(acc[mi][ni][0]);
        o4.y = f2bf(acc[mi][ni][1]);
        o4.z = f2bf(acc[mi][ni][2]);
        o4.w = f2bf(acc[mi][ni][3]);
        *(ushort4*)&dst[(((size_t)(b_ * NHEADS + h_)) * HDIM + d_) * TT + t_] = o4;
      } else {
#pragma unroll
        for (int r = 0; r < 4; ++r) {
          float v = acc[mi][ni][r] * sc;
          dst[(((size_t)(b_ * NHEADS + h_)) * TT + t_ + r) * HDIM + d_] = f2bf(v);
        }
      }
    }
  }
}

// Output projection: C = A W^T + bias, fp32 out. Same R8 dbuf structure,
// grid (64, 8) with m on x for XCD locality of the A (ow) tile.
__global__ __launch_bounds__(512, 4) void gemm_out(
    const unsigned short* __restrict__ A, const unsigned short* __restrict__ W,
    const float* __restrict__ bias, float* __restrict__ C)
{
  __shared__ unsigned short As[2][128 * 64];
  __shared__ unsigned short Bs[2][128 * 64];
  const int tid  = threadIdx.x;
  const int lane = tid & 63;
  const int wave = tid >> 6;
  const int lo   = lane & 15, q4 = lane >> 4;
  const int lo7  = lane & 7;
  const int wm   = wave & 3, wn = wave >> 2;
  const int m0 = blockIdx.x * 128, n0 = blockIdx.y * 128;

  f32x4 acc[2][4] = {};

  auto stage = [&](int k0, int buf) {
#pragma unroll
    for (int i = 0; i < 2; ++i) {
      int ci = i * 512 + tid;
      int row = ci >> 3;
      int c = (ci & 7) ^ (row & 7);
      async16(A + (size_t)(m0 + row) * DMODEL + k0 + c * 8, (char*)As[buf] + ci * 16);
      async16(W + (size_t)(n0 + row) * DMODEL + k0 + c * 8, (char*)Bs[buf] + ci * 16);
    }
  };

  stage(0, 0);
  for (int it = 0; it < DMODEL / 64; ++it) {
    const int buf = it & 1;
    __syncthreads();
    if (it + 1 < DMODEL / 64) stage((it + 1) * 64, buf ^ 1);
#pragma unroll
    for (int hh = 0; hh < 2; ++hh) {
      bf16x8 af[2], bf[4];
#pragma unroll
      for (int mi = 0; mi < 2; ++mi)
        af[mi] = *(const bf16x8*)&As[buf][(wm * 32 + mi * 16 + lo) * 64 + ((hh * 4 + q4) ^ lo7) * 8];
#pragma unroll
      for (int ni = 0; ni < 4; ++ni)
        bf[ni] = *(const bf16x8*)&Bs[buf][(wn * 64 + ni * 16 + lo) * 64 + ((hh * 4 + q4) ^ lo7) * 8];
#pragma unroll
      for (int mi = 0; mi < 2; ++mi)
#pragma unroll
        for (int ni = 0; ni < 4; ++ni)
          acc[mi][ni] = __builtin_amdgcn_mfma_f32_16x16x32_bf16(af[mi], bf[ni], acc[mi][ni], 0, 0, 0);
    }
  }

#pragma unroll
  for (int mi = 0; mi < 2; ++mi)
#pragma unroll
    for (int ni = 0; ni < 4; ++ni)
#pragma unroll
      for (int r = 0; r < 4; ++r) {
        int m = m0 + wm * 32 + mi * 16 + q4 * 4 + r;
        int n = n0 + wn * 64 + ni * 16 + lo;
        C[(size_t)m * DMODEL + n] = acc[mi][ni][r] + bias[n];
      }
}

// Flash attention + ALiBi, fixed-scale softmax, register-resident P (S^T trick),
// exact per-head sliding window, htab load-balancing.
// 8 waves x 32 q-rows = 256-row Q-block. PV at K=32 via permlane 4x4
// lane-group transpose. Row-sum on the VALU (f32, exact) + RNE P-pack
// (v_cvt_pk_bf16_f32) — replaces the 4 rowsum MFMAs per tile.
// XCD-group swizzle: the 8 qb-blocks of each (slot,b) group sit at bids
// spaced 8 apart -> same XCD under round-robin -> K/V window fetched
// into one L2 (per-XCD concurrent footprint ~3 MB < 4 MB).
__global__ __launch_bounds__(512, 4) void attn_kernel(
    const unsigned short* __restrict__ Q, const unsigned short* __restrict__ K,
    const unsigned short* __restrict__ Vt, unsigned short* __restrict__ O)
{
  __shared__ unsigned short Ks[2][64 * 64];
  __shared__ unsigned short Vs[2][64 * 64];

  const int tid = threadIdx.x, lane = tid & 63, wave = tid >> 6;  // wave 0..7
  const int lo = lane & 15, q4 = lane >> 4;
  const int lo7 = lane & 7;
  const int bid = blockIdx.x;  // 512 blocks
  // XCD-group decomposition: g = (bid&7) + 8*(bid>>6), qb = (bid>>3)&7
  const int g   = (bid & 7) + 8 * (bid >> 6);   // 0..63 group (slot,b)
  const int qb  = (bid >> 3) & 7;
  const int slot = g >> 2;
  const int b   = g & 3;
  // htab[s] packed as nibbles: {12,13,14,15,11,10,9,8,4,5,6,7,1,0,2,3}
  const int h  = (int)((0x3201765489ABFEDCull >> (slot * 4)) & 15);
  const int bh = b * NHEADS + h;
  const float slopeL = exp2f(-0.5f * (float)(h + 1)) * 1.44269504f;
  const int q0 = qb * 256;
  const int wq0 = q0 + wave * 32;

  // per-head window: keep tiles with min distance <= D = 28 exp2-bits
  const int D = (int)(19.407f * exp2f(0.5f * (float)(h + 1)));
  int tlo = q0 - D;
  const int ktlo = (tlo <= 0) ? 0 : (tlo >> 6);
  int thi = (q0 + 255 + D) >> 6;
  const int kthi = (thi > TT / 64 - 1) ? TT / 64 - 1 : thi;

  // Q fragments (B-operand of S^T): 2 m-tiles x 2 k-halves
  bf16x8 qf[2][2];
#pragma unroll
  for (int m = 0; m < 2; ++m)
#pragma unroll
    for (int hh = 0; hh < 2; ++hh)
      qf[m][hh] = *(const bf16x8*)(Q + ((size_t)bh * TT + wq0 + m * 16 + lo) * HDIM + hh * 32 + q4 * 8);

  f32x4 Oacc[2][4];
  float ps[2] = {0.f, 0.f};            // f32 row-sum (qrow = lo), per m-tile
#pragma unroll
  for (int m = 0; m < 2; ++m)
#pragma unroll
    for (int nd = 0; nd < 4; ++nd) Oacc[m][nd] = f32x4{0.f, 0.f, 0.f, 0.f};

  // hoisted distance base: qrow - key = eb[m][r] - (kt*64 + ns*16)
  float eb[2][4];
#pragma unroll
  for (int m = 0; m < 2; ++m)
#pragma unroll
    for (int r = 0; r < 4; ++r)
      eb[m][r] = (float)(wq0 + m * 16 + lo - q4 * 4 - r);

  const unsigned short* kbh = K + (size_t)bh * TT * HDIM;
  const unsigned short* vbh = Vt + (size_t)bh * HDIM * TT;

  // 512 threads: exactly one 16B chunk per thread per array per tile
  auto stage = [&](int kt, int buf) {
    int ci = tid;                      // 0..511
    int row = ci >> 3;
    int c = (ci & 7) ^ (row & 7);
    async16(kbh + (size_t)(kt * 64 + row) * HDIM + c * 8, (char*)Ks[buf] + ci * 16);
    async16(vbh + (size_t)row * TT + kt * 64 + c * 8,     (char*)Vs[buf] + ci * 16);
  };

  stage(ktlo, 0);

  for (int kt = ktlo; kt <= kthi; ++kt) {
    const int buf = (kt - ktlo) & 1;
    __syncthreads();  // tile kt staged; all waves done reading buf^1
    if (kt < kthi) stage(kt + 1, buf ^ 1);

#pragma unroll
    for (int pp = 0; pp < 2; ++pp) {       // 32-key half-tiles
      unsigned int ua[2][2], ub[2][2];     // [hns][m]: packed words (r0,r1)/(r2,r3)
#pragma unroll
      for (int hns = 0; hns < 2; ++hns) {
        const int ns = pp * 2 + hns;
        const int krow = (ns * 16 + lo) * 64;
        bf16x8 kf0 = *(const bf16x8*)&Ks[buf][krow + ((q4) ^ lo7) * 8];
        bf16x8 kf1 = *(const bf16x8*)&Ks[buf][krow + ((4 + q4) ^ lo7) * 8];
        const float kb = (float)(kt * 64 + ns * 16);
#pragma unroll
        for (int m = 0; m < 2; ++m) {
          // S^T: D[key][qrow], lane: col=lo=qrow, rows=q4*4+r=key-in-block
          f32x4 a = {0.f, 0.f, 0.f, 0.f};
          __builtin_amdgcn_s_setprio(1);
          a = __builtin_amdgcn_mfma_f32_16x16x32_bf16(kf0, qf[m][0], a, 0, 0, 0);
          a = __builtin_amdgcn_mfma_f32_16x16x32_bf16(kf1, qf[m][1], a, 0, 0, 0);
          __builtin_amdgcn_s_setprio(0);
          float pv[4];
#pragma unroll
          for (int r = 0; r < 4; ++r) {
            float w = eb[m][r] - kb;                      // qrow - key
            pv[r] = EXP2(fmaf(-slopeL, fabsf(w), a[r]));  // a already scaled by c1
          }
          ps[m] += (pv[0] + pv[1]) + (pv[2] + pv[3]);     // VALU row-sum
          ua[hns][m] = pkbf_rne(pv[0], pv[1]);
          ub[hns][m] = pkbf_rne(pv[2], pv[3]);
        }
      }

      // lane-group transpose: (q4'*4+r keys) -> (q4*8+j keys) K=32 A-fragment
      bf16x8 paf[2];
#pragma unroll
      for (int m = 0; m < 2; ++m) {
        unsigned int w0 = ua[0][m], w2 = ua[1][m];
        unsigned int w1 = ub[0][m], w3 = ub[1][m];
        asm("v_permlane32_swap_b32 %0, %1" : "+v"(w0), "+v"(w2));
        asm("v_permlane16_swap_b32 %0, %1" : "+v"(w0), "+v"(w2));  // w0=W0 w2=W2
        asm("v_permlane32_swap_b32 %0, %1" : "+v"(w1), "+v"(w3));
        asm("v_permlane16_swap_b32 %0, %1" : "+v"(w1), "+v"(w3));  // w1=W1 w3=W3
        union { bf16x8 v; unsigned int u[4]; } U;
        U.u[0] = w0; U.u[1] = w1; U.u[2] = w2; U.u[3] = w3;
        paf[m] = U.v;
      }

      // PV at K=32; B = Vt rows (n=d, k=key in 32-key half-tile)
#pragma unroll
      for (int nd = 0; nd < 4; ++nd) {
        const int row = nd * 16 + lo;
        bf16x8 vb = *(const bf16x8*)&Vs[buf][row * 64 + ((pp * 4 + q4) ^ lo7) * 8];
        __builtin_amdgcn_s_setprio(1);
#pragma unroll
        for (int m = 0; m < 2; ++m)
          Oacc[m][nd] = __builtin_amdgcn_mfma_f32_16x16x32_bf16(paf[m], vb, Oacc[m][nd], 0, 0, 0);
        __builtin_amdgcn_s_setprio(0);
      }
    }
  }

  // reduce row-sums across the 4 q4 lane-groups (qrow = lo after reduction)
#pragma unroll
  for (int m = 0; m < 2; ++m) {
    ps[m] += __shfl_xor(ps[m], 16);
    ps[m] += __shfl_xor(ps[m], 32);
  }

  // epilogue: fetch row-sum for qrow=q4*4+r from lane (q4*4+r), normalize, store
#pragma unroll
  for (int m = 0; m < 2; ++m)
#pragma unroll
    for (int r = 0; r < 4; ++r) {
      float l = __shfl(ps[m], q4 * 4 + r);
      float inv = 1.f / l;
      int t = wq0 + m * 16 + q4 * 4 + r;
#pragma unroll
      for (int nd = 0; nd < 4; ++nd) {
        int d = nd * 16 + lo;
        O[((size_t)(b * TT + t)) * DMODEL + h * HDIM + d] = f2bf(Oacc[m][nd][r] * inv);
      }
    }
}

extern "C" void kernel_launch(void* const* d_in, const int* in_sizes, int n_in,
                              void* d_out, int out_size, void* d_ws, size_t ws_size,
                              hipStream_t stream) {
  const float* x  = (const float*)d_in[0];
  const float* wq = (const float*)d_in[1];
  const float* wk = (const float*)d_in[2];
  const float* wv = (const float*)d_in[3];
  const float* wo = (const float*)d_in[4];
  const float* bo = (const float*)d_in[5];
  float* out = (float*)d_out;

  char* ws = (char*)d_ws;
  const size_t seg  = (size_t)BB * TT * DMODEL * sizeof(unsigned short);  // 16.78 MB
  const size_t wseg = (size_t)DMODEL * DMODEL * sizeof(unsigned short);   // 2 MB
  unsigned short* qw    = (unsigned short*)(ws);
  unsigned short* kw    = (unsigned short*)(ws + seg);
  unsigned short* vtw   = (unsigned short*)(ws + 2 * seg);
  unsigned short* ow    = (unsigned short*)(ws + 3 * seg);
  unsigned short* xb    = (unsigned short*)(ws + 4 * seg);
  unsigned short* wqkvb = (unsigned short*)(ws + 5 * seg);
  unsigned short* wob   = (unsigned short*)(ws + 5 * seg + 3 * wseg);

  cvt_all<<<dim3(8192 + 4096), dim3(256), 0, stream>>>(x, wq, wk, wv, wo, xb, wqkvb, wob);

  gemm_qkv<<<dim3(64, 24), dim3(512), 0, stream>>>(xb, wqkvb, qw, kw, vtw);

  attn_kernel<<<dim3(BB * NHEADS * (TT / 256)), dim3(512), 0, stream>>>(qw, kw, vtw, ow);

  gemm_out<<<dim3(64, 8), dim3(512), 0, stream>>>(ow, wob, bo, out);
}

// Round 6
// 231.984 us; speedup vs baseline: 1.1568x; 1.0082x over previous
//
#include <hip/hip_runtime.h>

#define DMODEL 1024
#define NHEADS 16
#define HDIM   64
#define BB     4
#define TT     2048

typedef __attribute__((ext_vector_type(8))) short bf16x8;
typedef __attribute__((ext_vector_type(4))) short bf16x4;
typedef __attribute__((ext_vector_type(4))) float f32x4;

#if __has_builtin(__builtin_amdgcn_exp2f)
#define EXP2(x) __builtin_amdgcn_exp2f(x)
#else
#define EXP2(x) __expf(0.69314718f * (x))
#endif

// 0.125 * log2(e): folded into Q at projection time
#define C1SCALE 0.18033688f

__device__ inline void async16(const void* g, void* l) {
  __builtin_amdgcn_global_load_lds(
      (const __attribute__((address_space(1))) unsigned int*)g,
      (__attribute__((address_space(3))) unsigned int*)l,
      16, 0, 0);
}

__device__ inline unsigned short f2bf(float x) {
  union { float f; unsigned int u; } c; c.f = x;
  unsigned int r = (c.u + 0x7FFFu + ((c.u >> 16) & 1u)) >> 16;
  return (unsigned short)r;
}

// pack two fp32 -> bf16x2 with RNE rounding (hardware v_cvt_pk_bf16_f32).
// lo16 = bf16(x), hi16 = bf16(y)
__device__ inline unsigned int pkbf_rne(float x, float y) {
  unsigned int r;
  asm("v_cvt_pk_bf16_f32 %0, %1, %2" : "=v"(r) : "v"(x), "v"(y));
  return r;
}

// One fused conversion kernel: x (8192 blk), wq/wk/wv -> wqkvb, wo -> wob (1024 blk each)
__global__ __launch_bounds__(256) void cvt_all(
    const float* __restrict__ x,  const float* __restrict__ wq,
    const float* __restrict__ wk, const float* __restrict__ wv,
    const float* __restrict__ wo,
    unsigned short* __restrict__ xb, unsigned short* __restrict__ wqkvb,
    unsigned short* __restrict__ wob)
{
  int bid = blockIdx.x;
  const float* src; unsigned short* dst; size_t off;
  if (bid < 8192) { src = x; dst = xb; off = (size_t)bid * 1024; }
  else {
    int w = (bid - 8192) >> 10, r = (bid - 8192) & 1023;
    off = (size_t)r * 1024;
    if (w == 0)      { src = wq; dst = wqkvb; }
    else if (w == 1) { src = wk; dst = wqkvb + 1048576; }
    else if (w == 2) { src = wv; dst = wqkvb + 2097152; }
    else             { src = wo; dst = wob; }
  }
  size_t i = off + threadIdx.x * 4;
  float4 v = *(const float4*)(src + i);
  ushort4 o;
  o.x = f2bf(v.x); o.y = f2bf(v.y); o.z = f2bf(v.z); o.w = f2bf(v.w);
  *(ushort4*)(dst + i) = o;
}

// Fused QKV projection: A = xb (8192x1024), W = wqkvb (3072x1024), y = A W^T.
// R8 structure: 8 waves x (32x64 per-wave tile, 32 AGPR acc), BK=64,
// XOR-8 swizzle (conflict-free), double-buffered async staging.
// Grid (64, 24): blockIdx.x = m-tile so same-m blocks (which share the A tile)
// have bids spaced 64 apart -> same XCD under round-robin -> A served from L2.
// Q output pre-scaled by C1SCALE. V-epilogue uses packed ushort4 stores.
__global__ __launch_bounds__(512, 4) void gemm_qkv(
    const unsigned short* __restrict__ A, const unsigned short* __restrict__ W,
    unsigned short* __restrict__ qw, unsigned short* __restrict__ kw,
    unsigned short* __restrict__ vtw)
{
  __shared__ unsigned short As[2][128 * 64];
  __shared__ unsigned short Bs[2][128 * 64];
  const int tid  = threadIdx.x;
  const int lane = tid & 63;
  const int wave = tid >> 6;           // 0..7
  const int lo   = lane & 15, q4 = lane >> 4;
  const int lo7  = lane & 7;
  const int wm   = wave & 3, wn = wave >> 2;  // 32-row quarter, 64-col half
  const int m0 = blockIdx.x * 128;            // m-tile on x (XCD locality)
  const int nb = blockIdx.y;                  // 0..23
  const int n0 = nb * 128;
  const int mid = nb >> 3;

  f32x4 acc[2][4] = {};

  auto stage = [&](int k0, int buf) {
#pragma unroll
    for (int i = 0; i < 2; ++i) {
      int ci = i * 512 + tid;          // 0..1023
      int row = ci >> 3;
      int c = (ci & 7) ^ (row & 7);
      async16(A + (size_t)(m0 + row) * DMODEL + k0 + c * 8, (char*)As[buf] + ci * 16);
      async16(W + (size_t)(n0 + row) * DMODEL + k0 + c * 8, (char*)Bs[buf] + ci * 16);
    }
  };

  stage(0, 0);
  for (int it = 0; it < DMODEL / 64; ++it) {
    const int buf = it & 1;
    __syncthreads();  // stage(it), issued one compute phase ago, now resident
    if (it + 1 < DMODEL / 64) stage((it + 1) * 64, buf ^ 1);
#pragma unroll
    for (int hh = 0; hh < 2; ++hh) {
      bf16x8 af[2], bf[4];
#pragma unroll
      for (int mi = 0; mi < 2; ++mi)
        af[mi] = *(const bf16x8*)&As[buf][(wm * 32 + mi * 16 + lo) * 64 + ((hh * 4 + q4) ^ lo7) * 8];
#pragma unroll
      for (int ni = 0; ni < 4; ++ni)
        bf[ni] = *(const bf16x8*)&Bs[buf][(wn * 64 + ni * 16 + lo) * 64 + ((hh * 4 + q4) ^ lo7) * 8];
#pragma unroll
      for (int mi = 0; mi < 2; ++mi)
#pragma unroll
        for (int ni = 0; ni < 4; ++ni)
          acc[mi][ni] = __builtin_amdgcn_mfma_f32_16x16x32_bf16(af[mi], bf[ni], acc[mi][ni], 0, 0, 0);
    }
  }

  unsigned short* dst = (mid == 0) ? qw : (mid == 1) ? kw : vtw;
  const float sc = (mid == 0) ? C1SCALE : 1.0f;
#pragma unroll
  for (int mi = 0; mi < 2; ++mi) {
#pragma unroll
    for (int ni = 0; ni < 4; ++ni) {
      int m_ = m0 + wm * 32 + mi * 16 + q4 * 4;      // t0 (multiple of 4)
      int nl = ((nb & 7) * 128) + wn * 64 + ni * 16 + lo;
      int b_ = m_ >> 11, t_ = m_ & (TT - 1);
      int h_ = nl >> 6, d_ = nl & 63;
      if (mid == 2) {
        ushort4 o4;
        o4.x = f2bf(acc[mi][ni][0]);
        o4.y = f2bf(acc[mi][ni][1]);
        o4.z = f2bf(acc[mi][ni][2]);
        o4.w = f2bf(acc[mi][ni][3]);
        *(ushort4*)&dst[(((size_t)(b_ * NHEADS + h_)) * HDIM + d_) * TT + t_] = o4;
      } else {
#pragma unroll
        for (int r = 0; r < 4; ++r) {
          float v = acc[mi][ni][r] * sc;
          dst[(((size_t)(b_ * NHEADS + h_)) * TT + t_ + r) * HDIM + d_] = f2bf(v);
        }
      }
    }
  }
}

// Output projection: C = A W^T + bias, fp32 out. Same R8 dbuf structure,
// grid (64, 8) with m on x for XCD locality of the A (ow) tile.
__global__ __launch_bounds__(512, 4) void gemm_out(
    const unsigned short* __restrict__ A, const unsigned short* __restrict__ W,
    const float* __restrict__ bias, float* __restrict__ C)
{
  __shared__ unsigned short As[2][128 * 64];
  __shared__ unsigned short Bs[2][128 * 64];
  const int tid  = threadIdx.x;
  const int lane = tid & 63;
  const int wave = tid >> 6;
  const int lo   = lane & 15, q4 = lane >> 4;
  const int lo7  = lane & 7;
  const int wm   = wave & 3, wn = wave >> 2;
  const int m0 = blockIdx.x * 128, n0 = blockIdx.y * 128;

  f32x4 acc[2][4] = {};

  auto stage = [&](int k0, int buf) {
#pragma unroll
    for (int i = 0; i < 2; ++i) {
      int ci = i * 512 + tid;
      int row = ci >> 3;
      int c = (ci & 7) ^ (row & 7);
      async16(A + (size_t)(m0 + row) * DMODEL + k0 + c * 8, (char*)As[buf] + ci * 16);
      async16(W + (size_t)(n0 + row) * DMODEL + k0 + c * 8, (char*)Bs[buf] + ci * 16);
    }
  };

  stage(0, 0);
  for (int it = 0; it < DMODEL / 64; ++it) {
    const int buf = it & 1;
    __syncthreads();
    if (it + 1 < DMODEL / 64) stage((it + 1) * 64, buf ^ 1);
#pragma unroll
    for (int hh = 0; hh < 2; ++hh) {
      bf16x8 af[2], bf[4];
#pragma unroll
      for (int mi = 0; mi < 2; ++mi)
        af[mi] = *(const bf16x8*)&As[buf][(wm * 32 + mi * 16 + lo) * 64 + ((hh * 4 + q4) ^ lo7) * 8];
#pragma unroll
      for (int ni = 0; ni < 4; ++ni)
        bf[ni] = *(const bf16x8*)&Bs[buf][(wn * 64 + ni * 16 + lo) * 64 + ((hh * 4 + q4) ^ lo7) * 8];
#pragma unroll
      for (int mi = 0; mi < 2; ++mi)
#pragma unroll
        for (int ni = 0; ni < 4; ++ni)
          acc[mi][ni] = __builtin_amdgcn_mfma_f32_16x16x32_bf16(af[mi], bf[ni], acc[mi][ni], 0, 0, 0);
    }
  }

#pragma unroll
  for (int mi = 0; mi < 2; ++mi)
#pragma unroll
    for (int ni = 0; ni < 4; ++ni)
#pragma unroll
      for (int r = 0; r < 4; ++r) {
        int m = m0 + wm * 32 + mi * 16 + q4 * 4 + r;
        int n = n0 + wn * 64 + ni * 16 + lo;
        C[(size_t)m * DMODEL + n] = acc[mi][ni][r] + bias[n];
      }
}

// Flash attention + ALiBi, fixed-scale softmax, register-resident P (S^T trick),
// exact per-head sliding window. 8 waves x 32 q-rows = 256-row Q-block.
// PV at K=32 via permlane 4x4 lane-group transpose; VALU f32 row-sum +
// RNE P-pack. XCD-group swizzle: 8 qb-blocks of each (slot,b) on one XCD.
// htab is the LPT pairing: slots 0-7 = heads 15..8 (heavy, dispatched first),
// slots 8-15 = heads 0..7; CU co-resident pair (slot s, slot s+8) = heads
// (15-s, s) -> per-CU load equalized (max 46.7 -> 41.8 tiles).
// Wave-level window skip: a wave skips compute for key-tiles outside its own
// 32-row window [wq0-D, wq0+31+D] (same D semantics as the block-level bound).
__global__ __launch_bounds__(512, 4) void attn_kernel(
    const unsigned short* __restrict__ Q, const unsigned short* __restrict__ K,
    const unsigned short* __restrict__ Vt, unsigned short* __restrict__ O)
{
  __shared__ unsigned short Ks[2][64 * 64];
  __shared__ unsigned short Vs[2][64 * 64];

  const int tid = threadIdx.x, lane = tid & 63, wave = tid >> 6;  // wave 0..7
  const int lo = lane & 15, q4 = lane >> 4;
  const int lo7 = lane & 7;
  const int bid = blockIdx.x;  // 512 blocks
  // XCD-group decomposition: g = (bid&7) + 8*(bid>>6), qb = (bid>>3)&7
  const int g   = (bid & 7) + 8 * (bid >> 6);   // 0..63 group (slot,b)
  const int qb  = (bid >> 3) & 7;
  const int slot = g >> 2;
  const int b   = g & 3;
  // LPT-pair htab: slot s -> head; {15,14,13,12,11,10,9,8,0,1,2,3,4,5,6,7}
  const int h  = (int)((0x7654321089ABCDEFull >> (slot * 4)) & 15);
  const int bh = b * NHEADS + h;
  const float slopeL = exp2f(-0.5f * (float)(h + 1)) * 1.44269504f;
  const int q0 = qb * 256;
  const int wq0 = q0 + wave * 32;

  // per-head window: keep tiles with min distance <= D = 28 exp2-bits
  const int D = (int)(19.407f * exp2f(0.5f * (float)(h + 1)));
  int tlo = q0 - D;
  const int ktlo = (tlo <= 0) ? 0 : (tlo >> 6);
  int thi = (q0 + 255 + D) >> 6;
  const int kthi = (thi > TT / 64 - 1) ? TT / 64 - 1 : thi;
  // this wave's own window (32 rows)
  const int wlo = wq0 - D;
  const int whi = wq0 + 31 + D;

  // Q fragments (B-operand of S^T): 2 m-tiles x 2 k-halves
  bf16x8 qf[2][2];
#pragma unroll
  for (int m = 0; m < 2; ++m)
#pragma unroll
    for (int hh = 0; hh < 2; ++hh)
      qf[m][hh] = *(const bf16x8*)(Q + ((size_t)bh * TT + wq0 + m * 16 + lo) * HDIM + hh * 32 + q4 * 8);

  f32x4 Oacc[2][4];
  float ps[2] = {0.f, 0.f};            // f32 row-sum (qrow = lo), per m-tile
#pragma unroll
  for (int m = 0; m < 2; ++m)
#pragma unroll
    for (int nd = 0; nd < 4; ++nd) Oacc[m][nd] = f32x4{0.f, 0.f, 0.f, 0.f};

  // hoisted distance base: qrow - key = eb[m][r] - (kt*64 + ns*16)
  float eb[2][4];
#pragma unroll
  for (int m = 0; m < 2; ++m)
#pragma unroll
    for (int r = 0; r < 4; ++r)
      eb[m][r] = (float)(wq0 + m * 16 + lo - q4 * 4 - r);

  const unsigned short* kbh = K + (size_t)bh * TT * HDIM;
  const unsigned short* vbh = Vt + (size_t)bh * HDIM * TT;

  // 512 threads: exactly one 16B chunk per thread per array per tile
  auto stage = [&](int kt, int buf) {
    int ci = tid;                      // 0..511
    int row = ci >> 3;
    int c = (ci & 7) ^ (row & 7);
    async16(kbh + (size_t)(kt * 64 + row) * HDIM + c * 8, (char*)Ks[buf] + ci * 16);
    async16(vbh + (size_t)row * TT + kt * 64 + c * 8,     (char*)Vs[buf] + ci * 16);
  };

  stage(ktlo, 0);

  for (int kt = ktlo; kt <= kthi; ++kt) {
    const int buf = (kt - ktlo) & 1;
    __syncthreads();  // tile kt staged; all waves done reading buf^1
    if (kt < kthi) stage(kt + 1, buf ^ 1);

    // wave-uniform window test: skip compute if this tile can't contribute
    const bool active = (kt * 64 <= whi) && (kt * 64 + 63 >= wlo);
    if (active) {
#pragma unroll
    for (int pp = 0; pp < 2; ++pp) {       // 32-key half-tiles
      unsigned int ua[2][2], ub[2][2];     // [hns][m]: packed words (r0,r1)/(r2,r3)
#pragma unroll
      for (int hns = 0; hns < 2; ++hns) {
        const int ns = pp * 2 + hns;
        const int krow = (ns * 16 + lo) * 64;
        bf16x8 kf0 = *(const bf16x8*)&Ks[buf][krow + ((q4) ^ lo7) * 8];
        bf16x8 kf1 = *(const bf16x8*)&Ks[buf][krow + ((4 + q4) ^ lo7) * 8];
        const float kb = (float)(kt * 64 + ns * 16);
#pragma unroll
        for (int m = 0; m < 2; ++m) {
          // S^T: D[key][qrow], lane: col=lo=qrow, rows=q4*4+r=key-in-block
          f32x4 a = {0.f, 0.f, 0.f, 0.f};
          __builtin_amdgcn_s_setprio(1);
          a = __builtin_amdgcn_mfma_f32_16x16x32_bf16(kf0, qf[m][0], a, 0, 0, 0);
          a = __builtin_amdgcn_mfma_f32_16x16x32_bf16(kf1, qf[m][1], a, 0, 0, 0);
          __builtin_amdgcn_s_setprio(0);
          float pv[4];
#pragma unroll
          for (int r = 0; r < 4; ++r) {
            float w = eb[m][r] - kb;                      // qrow - key
            pv[r] = EXP2(fmaf(-slopeL, fabsf(w), a[r]));  // a already scaled by c1
          }
          ps[m] += (pv[0] + pv[1]) + (pv[2] + pv[3]);     // VALU row-sum
          ua[hns][m] = pkbf_rne(pv[0], pv[1]);
          ub[hns][m] = pkbf_rne(pv[2], pv[3]);
        }
      }

      // lane-group transpose: (q4'*4+r keys) -> (q4*8+j keys) K=32 A-fragment
      bf16x8 paf[2];
#pragma unroll
      for (int m = 0; m < 2; ++m) {
        unsigned int w0 = ua[0][m], w2 = ua[1][m];
        unsigned int w1 = ub[0][m], w3 = ub[1][m];
        asm("v_permlane32_swap_b32 %0, %1" : "+v"(w0), "+v"(w2));
        asm("v_permlane16_swap_b32 %0, %1" : "+v"(w0), "+v"(w2));  // w0=W0 w2=W2
        asm("v_permlane32_swap_b32 %0, %1" : "+v"(w1), "+v"(w3));
        asm("v_permlane16_swap_b32 %0, %1" : "+v"(w1), "+v"(w3));  // w1=W1 w3=W3
        union { bf16x8 v; unsigned int u[4]; } U;
        U.u[0] = w0; U.u[1] = w1; U.u[2] = w2; U.u[3] = w3;
        paf[m] = U.v;
      }

      // PV at K=32; B = Vt rows (n=d, k=key in 32-key half-tile)
#pragma unroll
      for (int nd = 0; nd < 4; ++nd) {
        const int row = nd * 16 + lo;
        bf16x8 vb = *(const bf16x8*)&Vs[buf][row * 64 + ((pp * 4 + q4) ^ lo7) * 8];
        __builtin_amdgcn_s_setprio(1);
#pragma unroll
        for (int m = 0; m < 2; ++m)
          Oacc[m][nd] = __builtin_amdgcn_mfma_f32_16x16x32_bf16(paf[m], vb, Oacc[m][nd], 0, 0, 0);
        __builtin_amdgcn_s_setprio(0);
      }
    }
    }  // active
  }

  // reduce row-sums across the 4 q4 lane-groups (qrow = lo after reduction)
#pragma unroll
  for (int m = 0; m < 2; ++m) {
    ps[m] += __shfl_xor(ps[m], 16);
    ps[m] += __shfl_xor(ps[m], 32);
  }

  // epilogue: fetch row-sum for qrow=q4*4+r from lane (q4*4+r), normalize, store
#pragma unroll
  for (int m = 0; m < 2; ++m)
#pragma unroll
    for (int r = 0; r < 4; ++r) {
      float l = __shfl(ps[m], q4 * 4 + r);
      float inv = 1.f / l;
      int t = wq0 + m * 16 + q4 * 4 + r;
#pragma unroll
      for (int nd = 0; nd < 4; ++nd) {
        int d = nd * 16 + lo;
        O[((size_t)(b * TT + t)) * DMODEL + h * HDIM + d] = f2bf(Oacc[m][nd][r] * inv);
      }
    }
}

extern "C" void kernel_launch(void* const* d_in, const int* in_sizes, int n_in,
                              void* d_out, int out_size, void* d_ws, size_t ws_size,
                              hipStream_t stream) {
  const float* x  = (const float*)d_in[0];
  const float* wq = (const float*)d_in[1];
  const float* wk = (const float*)d_in[2];
  const float* wv = (const float*)d_in[3];
  const float* wo = (const float*)d_in[4];
  const float* bo = (const float*)d_in[5];
  float* out = (float*)d_out;

  char* ws = (char*)d_ws;
  const size_t seg  = (size_t)BB * TT * DMODEL * sizeof(unsigned short);  // 16.78 MB
  const size_t wseg = (size_t)DMODEL * DMODEL * sizeof(unsigned short);   // 2 MB
  unsigned short* qw    = (unsigned short*)(ws);
  unsigned short* kw    = (unsigned short*)(ws + seg);
  unsigned short* vtw   = (unsigned short*)(ws + 2 * seg);
  unsigned short* ow    = (unsigned short*)(ws + 3 * seg);
  unsigned short* xb    = (unsigned short*)(ws + 4 * seg);
  unsigned short* wqkvb = (unsigned short*)(ws + 5 * seg);
  unsigned short* wob   = (unsigned short*)(ws + 5 * seg + 3 * wseg);

  cvt_all<<<dim3(8192 + 4096), dim3(256), 0, stream>>>(x, wq, wk, wv, wo, xb, wqkvb, wob);

  gemm_qkv<<<dim3(64, 24), dim3(512), 0, stream>>>(xb, wqkvb, qw, kw, vtw);

  attn_kernel<<<dim3(BB * NHEADS * (TT / 256)), dim3(512), 0, stream>>>(qw, kw, vtw, ow);

  gemm_out<<<dim3(64, 8), dim3(512), 0, stream>>>(ow, wob, bo, out);
}